// Round 3
// baseline (581.193 us; speedup 1.0000x reference)
//
#include <hip/hip_runtime.h>

#define OUT_W 7
#define OUT_L 7
#define OUT_H 7
#define SR 2
#define CDIM 128
#define WDIM 64
#define LDIM 64
#define HDIM 64
#define VOLSZ (WDIM * LDIM * HDIM)
#define CPB 2
#define NSAMP (OUT_W * SR * OUT_L * SR)   // 196 xy sub-samples
#define CSTRIDE 52                        // 13 float4 per sample slot (odd-f4 stride: bank spread)

typedef float f4 __attribute__((ext_vector_type(4)));

// Compiler-proof deep load batch (same discipline as R4/R5): volatile asm loads
// stay issued back-to-back; results usable only through the s_waitcnt tie.
#define GLOAD(dst, p)   asm volatile("global_load_dwordx4 %0, %1, off"           : "=v"(dst) : "v"(p))
#define GLOADO(dst, p)  asm volatile("global_load_dwordx4 %0, %1, off offset:16" : "=v"(dst) : "v"(p))

static __device__ __forceinline__ f4 interp4(float w00, float w10, float w01, float w11,
                                             f4 a, f4 b, f4 c, f4 d) {
    f4 o;
    o.x = w00*a.x + w10*b.x + w01*c.x + w11*d.x;
    o.y = w00*a.y + w10*b.y + w01*c.y + w11*d.y;
    o.z = w00*a.z + w10*b.z + w01*c.z + w11*d.z;
    o.w = w00*a.w + w10*b.w + w01*c.w + w11*d.w;
    return o;
}

// R6: sample-major restructure. Trilinear interpolation is separable, so the
// xy-interpolated column of each of the 196 sub-samples is computed ONCE
// (phase 1: 196 threads, 4 corner columns x 2 ch over the block-uniform
// z-window, runtime chunk-pair loop, 16 loads forced in-flight) and staged in
// LDS. Phase 2: 343 bin-threads z-dot 4 samples' windows from LDS.
// Cuts per-block VMEM lane-loads 22.0K -> ~12.5K and L1<->L2 traffic ~3x --
// R5 showed we are request-throughput-bound (FETCH 4.4x down, dur only -13%).
__global__ __launch_bounds__(384) void roi_align_rot3d_kernel(
    const float* __restrict__ input, const float* __restrict__ rois,
    const float* __restrict__ scale_ptr, float* __restrict__ out, int N)
{
    __shared__ alignas(16) float icol[CPB][NSAMP][CSTRIDE];  // 81,536 B (2 blocks/CU: 81,788 -> 81,920 rounded)
    __shared__ alignas(16) float zw[OUT_H][8];               // 7 x 8 z-filter taps
    __shared__ int zb4s[OUT_H];                              // 7 aligned window bases

    // bijective XCD-chunked remap (kept from R5: FETCH 610->138 MB)
    const int nwg = N * (CDIM / CPB);
    const int q = nwg >> 3, rr = nwg & 7;
    const int xcd = blockIdx.x & 7;
    const int idx_in = blockIdx.x >> 3;
    const int wk = (xcd < rr ? xcd * (q + 1) : rr * (q + 1) + (xcd - rr) * q) + idx_in;
    const int cp = wk / N;          // channel-pair: slow axis (slice stays in L2)
    const int n  = wk - cp * N;     // ROI: fast axis (cross-ROI L2 reuse)
    const int c0 = cp * CPB;
    const int t = threadIdx.x;

    const float scale = scale_ptr[0];
    const float* r = rois + (size_t)n * 8;
    const int   b  = (int)r[0];
    const float cx = r[1] * scale, cy = r[2] * scale, cz = r[3] * scale;
    const float sx = r[4] * scale, sy = r[5] * scale, szv = r[6] * scale;
    const float th = r[7];
    const float ct = cosf(th), st = sinf(th);

    // per-sample xy geometry stays in registers (no cols[] LDS needed)
    int b00 = 0, b10 = 0, b01 = 0, b11 = 0;
    float w00 = 0.f, w10 = 0.f, w01 = 0.f, w11 = 0.f;

    if (t < NSAMP) {
        const int isx = t / 14, isy = t - isx * 14;
        const float xx = -0.5f * sx + ((float)isx + 0.5f) * (sx * (1.0f / 14.0f));
        const float yy = -0.5f * sy + ((float)isy + 0.5f) * (sy * (1.0f / 14.0f));
        float x = ct * xx - st * yy + cx;
        float y = st * xx + ct * yy + cy;
        const bool v = (x > -1.0f) && (x < (float)WDIM) && (y > -1.0f) && (y < (float)LDIM);
        x = fminf(fmaxf(x, 0.0f), (float)(WDIM - 1));
        y = fminf(fmaxf(y, 0.0f), (float)(LDIM - 1));
        const int x0 = (int)floorf(x);
        const int y0 = (int)floorf(y);
        const int x1 = min(x0 + 1, WDIM - 1);
        const int y1 = min(y0 + 1, LDIM - 1);
        const float lx = x - (float)x0, ly = y - (float)y0;
        const float hx = 1.0f - lx, hy = 1.0f - ly;
        const float vm = v ? 1.0f : 0.0f;
        b00 = x0 * (LDIM * HDIM) + y0 * HDIM;
        b10 = x1 * (LDIM * HDIM) + y0 * HDIM;
        b01 = x0 * (LDIM * HDIM) + y1 * HDIM;
        b11 = x1 * (LDIM * HDIM) + y1 * HDIM;
        w00 = hx * hy * vm; w10 = lx * hy * vm;
        w01 = hx * ly * vm; w11 = lx * ly * vm;
    } else if (t < NSAMP + OUT_H) {   // one thread per output z-bin: 8-tap z filter
        const int oh = t - NSAMP;
        float w8[8];
        #pragma unroll
        for (int k = 0; k < 8; ++k) w8[k] = 0.0f;
        int zb4 = 0;
        #pragma unroll
        for (int dz = 0; dz < 2; ++dz) {
            const int s = oh * 2 + dz;
            const float zraw = -0.5f * szv + ((float)s + 0.5f) * (szv * (1.0f / 14.0f)) + cz;
            const bool v = (zraw > -1.0f) && (zraw < (float)HDIM);
            const float z = fminf(fmaxf(zraw, 0.0f), (float)(HDIM - 1));
            const int z0 = (int)floorf(z);
            const int z1 = min(z0 + 1, HDIM - 1);
            const float lz = z - (float)z0, hz = 1.0f - lz;
            const float vm = v ? 1.0f : 0.0f;
            if (dz == 0) zb4 = min(z0 & ~3, HDIM - 8);
            w8[z0 - zb4] += hz * vm;
            w8[z1 - zb4] += lz * vm;
        }
        zb4s[oh] = zb4;
        #pragma unroll
        for (int k = 0; k < 8; ++k) zw[oh][k] = w8[k];
    }
    __syncthreads();

    // block-uniform z window: [zbase, zbase + 4*nch), nch made even for pair loop.
    // zb4s is monotone non-decreasing; span <= 36 floats => nch <= 10 <= 12 slots.
    int zbase = zb4s[0];
    int nch = ((zb4s[6] + 8) - zbase) >> 2;
    if (nch & 1) { if (zbase >= 4) zbase -= 4; nch += 1; }
    const int npairs = nch >> 1;

    if (t < NSAMP) {
        const float* base = input + (size_t)(b * CDIM + c0) * (size_t)VOLSZ + zbase;
        const float* p00 = base + b00;
        const float* p10 = base + b10;
        const float* p01 = base + b01;
        const float* p11 = base + b11;
        const float* q00 = p00 + VOLSZ;
        const float* q10 = p10 + VOLSZ;
        const float* q01 = p01 + VOLSZ;
        const float* q11 = p11 + VOLSZ;
        float* l0 = &icol[0][t][0];
        float* l1 = &icol[1][t][0];
        for (int kp = 0; kp < npairs; ++kp) {
            f4 r00, r01, r02, r03, r04, r05, r06, r07;
            f4 r08, r09, r10, r11, r12, r13, r14, r15;
            GLOAD(r00, p00); GLOADO(r01, p00);
            GLOAD(r02, p10); GLOADO(r03, p10);
            GLOAD(r04, p01); GLOADO(r05, p01);
            GLOAD(r06, p11); GLOADO(r07, p11);
            GLOAD(r08, q00); GLOADO(r09, q00);
            GLOAD(r10, q10); GLOADO(r11, q10);
            GLOAD(r12, q01); GLOADO(r13, q01);
            GLOAD(r14, q11); GLOADO(r15, q11);
            asm volatile("s_waitcnt vmcnt(0)"
                : "+v"(r00), "+v"(r01), "+v"(r02), "+v"(r03),
                  "+v"(r04), "+v"(r05), "+v"(r06), "+v"(r07),
                  "+v"(r08), "+v"(r09), "+v"(r10), "+v"(r11),
                  "+v"(r12), "+v"(r13), "+v"(r14), "+v"(r15));
            *(f4*)(l0 + 8 * kp)     = interp4(w00, w10, w01, w11, r00, r02, r04, r06);
            *(f4*)(l0 + 8 * kp + 4) = interp4(w00, w10, w01, w11, r01, r03, r05, r07);
            *(f4*)(l1 + 8 * kp)     = interp4(w00, w10, w01, w11, r08, r10, r12, r14);
            *(f4*)(l1 + 8 * kp + 4) = interp4(w00, w10, w01, w11, r09, r11, r13, r15);
            p00 += 8; p10 += 8; p01 += 8; p11 += 8;
            q00 += 8; q10 += 8; q01 += 8; q11 += 8;
        }
    }
    __syncthreads();

    if (t >= 343) return;
    const int ow = t / 49;
    const int rem = t - ow * 49;
    const int ol = rem / 7;
    const int oh = rem - ol * 7;

    const f4 zwa = *(const f4*)&zw[oh][0];
    const f4 zwb = *(const f4*)&zw[oh][4];
    const int off = zb4s[oh] - zbase;   // multiple of 4; off+7 < CSTRIDE

    float acc0 = 0.0f, acc1 = 0.0f;
    #pragma unroll
    for (int dx = 0; dx < 2; ++dx) {
        #pragma unroll
        for (int dy = 0; dy < 2; ++dy) {
            const int s = (ow * 2 + dx) * 14 + (ol * 2 + dy);
            const f4 va = *(const f4*)&icol[0][s][off];
            const f4 vb = *(const f4*)&icol[0][s][off + 4];
            acc0 += zwa.x*va.x + zwa.y*va.y + zwa.z*va.z + zwa.w*va.w
                  + zwb.x*vb.x + zwb.y*vb.y + zwb.z*vb.z + zwb.w*vb.w;
            const f4 ua = *(const f4*)&icol[1][s][off];
            const f4 ub = *(const f4*)&icol[1][s][off + 4];
            acc1 += zwa.x*ua.x + zwa.y*ua.y + zwa.z*ua.z + zwa.w*ua.w
                  + zwb.x*ub.x + zwb.y*ub.y + zwb.z*ub.z + zwb.w*ub.w;
        }
    }
    out[((size_t)(n * CDIM + c0 + 0)) * 343 + t] = acc0 * 0.125f;
    out[((size_t)(n * CDIM + c0 + 1)) * 343 + t] = acc1 * 0.125f;
}

extern "C" void kernel_launch(void* const* d_in, const int* in_sizes, int n_in,
                              void* d_out, int out_size, void* d_ws, size_t ws_size,
                              hipStream_t stream) {
    const float* input = (const float*)d_in[0];
    const float* rois  = (const float*)d_in[1];
    const float* scale = (const float*)d_in[2];
    float* out = (float*)d_out;
    const int N = in_sizes[1] / 8;
    dim3 grid((unsigned)(N * (CDIM / CPB)));
    dim3 block(384);
    hipLaunchKernelGGL(roi_align_rot3d_kernel, grid, block, 0, stream,
                       input, rois, scale, out, N);
}

// Round 4
// 483.519 us; speedup vs baseline: 1.2020x; 1.2020x over previous
//
#include <hip/hip_runtime.h>

#define OUT_W 7
#define OUT_L 7
#define OUT_H 7
#define SR 2
#define CDIM 128
#define WDIM 64
#define LDIM 64
#define HDIM 64
#define VOLSZ (WDIM * LDIM * HDIM)
#define NSAMP (OUT_W * SR * OUT_L * SR)   // 196 xy sub-samples
#define CSTRIDE 52   // floats per icol row: 48 data + 4 pad (52%8==4 -> period-8 bank-quad spread)
#define WINF 48      // block-uniform staged z-window (floats); span proof: zb4 span<=33+8<=41<=48
#define NGROUPS 96   // 384 threads / 4 lanes

typedef float f4 __attribute__((ext_vector_type(4)));

// Deep-load discipline (R4/R5-proven): volatile asm loads issue back-to-back;
// results usable only through the s_waitcnt that ties the regs.
#define GLOAD0(dst, p)  asm volatile("global_load_dwordx4 %0, %1, off"           : "=v"(dst) : "v"(p))
#define GLOAD16(dst, p) asm volatile("global_load_dwordx4 %0, %1, off offset:16" : "=v"(dst) : "v"(p))
#define GLOAD32(dst, p) asm volatile("global_load_dwordx4 %0, %1, off offset:32" : "=v"(dst) : "v"(p))

// R7: coalesced separable staging.
//  - R5 showed FETCH fixed (XCD swizzle) but time ~ scattered-line throughput.
//  - R6 showed per-thread staging DE-coalesces (64 lines/instr) + LDS/occupancy blowup.
//  - Here: 4-lane groups stage one sample's xy-interpolated 48-float column.
//    Each wave VMEM instr = 16 groups x one 64B line, 4 lanes per line (ideal).
//    Corners accumulate in registers (no LDS RMW). CPB=1 keeps LDS ~47KB -> 3 blocks/CU.
__global__ __launch_bounds__(384, 5) void roi_align_rot3d_kernel(
    const float* __restrict__ input, const float* __restrict__ rois,
    const float* __restrict__ scale_ptr, float* __restrict__ out, int N)
{
    __shared__ int4   colb[NSAMP];                      // 4 corner column bases (voxel idx)
    __shared__ float4 colw[NSAMP];                      // 4 corner xy-weights
    __shared__ alignas(16) float icol[NSAMP][CSTRIDE];  // 40,768 B interpolated columns
    __shared__ alignas(16) float zw[OUT_H][8];          // 8-tap z filters
    __shared__ int zb4s[OUT_H];                         // per-bin aligned window base

    // bijective XCD-chunked remap (R5: FETCH 610->138 MB; keep)
    const int nwg = N * CDIM;
    const int q = nwg >> 3, rr = nwg & 7;
    const int xcd = blockIdx.x & 7;
    const int idx_in = blockIdx.x >> 3;
    const int wk = (xcd < rr ? xcd * (q + 1) : rr * (q + 1) + (xcd - rr) * q) + idx_in;
    const int c0 = wk / N;          // channel: slow axis (1.9MB slice stays in XCD L2)
    const int n  = wk - c0 * N;     // ROI: fast axis (cross-ROI L2 reuse)
    const int t = threadIdx.x;

    const float scale = scale_ptr[0];
    const float* r = rois + (size_t)n * 8;
    const int   b  = (int)r[0];
    const float cx = r[1] * scale, cy = r[2] * scale, cz = r[3] * scale;
    const float sx = r[4] * scale, sy = r[5] * scale, szv = r[6] * scale;
    const float th = r[7];
    const float ct = cosf(th), st = sinf(th);

    if (t < NSAMP) {
        const int isx = t / 14, isy = t - isx * 14;
        const float xx = -0.5f * sx + ((float)isx + 0.5f) * (sx * (1.0f / 14.0f));
        const float yy = -0.5f * sy + ((float)isy + 0.5f) * (sy * (1.0f / 14.0f));
        float x = ct * xx - st * yy + cx;
        float y = st * xx + ct * yy + cy;
        const bool v = (x > -1.0f) && (x < (float)WDIM) && (y > -1.0f) && (y < (float)LDIM);
        x = fminf(fmaxf(x, 0.0f), (float)(WDIM - 1));
        y = fminf(fmaxf(y, 0.0f), (float)(LDIM - 1));
        const int x0 = (int)floorf(x);
        const int y0 = (int)floorf(y);
        const int x1 = min(x0 + 1, WDIM - 1);
        const int y1 = min(y0 + 1, LDIM - 1);
        const float lx = x - (float)x0, ly = y - (float)y0;
        const float hx = 1.0f - lx, hy = 1.0f - ly;
        const float vm = v ? 1.0f : 0.0f;
        int4 cb;
        cb.x = x0 * (LDIM * HDIM) + y0 * HDIM;
        cb.y = x1 * (LDIM * HDIM) + y0 * HDIM;
        cb.z = x0 * (LDIM * HDIM) + y1 * HDIM;
        cb.w = x1 * (LDIM * HDIM) + y1 * HDIM;
        colb[t] = cb;
        float4 cw;
        cw.x = hx * hy * vm; cw.y = lx * hy * vm;
        cw.z = hx * ly * vm; cw.w = lx * ly * vm;
        colw[t] = cw;
    } else if (t < NSAMP + OUT_H) {   // one thread per z-bin: fold 2 sub-samples x 2 taps
        const int oh = t - NSAMP;
        float w8[8];
        #pragma unroll
        for (int k = 0; k < 8; ++k) w8[k] = 0.0f;
        int zb4 = 0;
        #pragma unroll
        for (int dz = 0; dz < 2; ++dz) {
            const int s = oh * 2 + dz;
            const float zraw = -0.5f * szv + ((float)s + 0.5f) * (szv * (1.0f / 14.0f)) + cz;
            const bool v = (zraw > -1.0f) && (zraw < (float)HDIM);
            const float z = fminf(fmaxf(zraw, 0.0f), (float)(HDIM - 1));
            const int z0 = (int)floorf(z);
            const int z1 = min(z0 + 1, HDIM - 1);
            const float lz = z - (float)z0, hz = 1.0f - lz;
            const float vm = v ? 1.0f : 0.0f;
            if (dz == 0) zb4 = min(z0 & ~3, HDIM - 8);
            w8[z0 - zb4] += hz * vm;
            w8[z1 - zb4] += lz * vm;
        }
        zb4s[oh] = zb4;
        #pragma unroll
        for (int k = 0; k < 8; ++k) zw[oh][k] = w8[k];
    }
    __syncthreads();

    // Block-uniform window [zbase, zbase+48): covers every bin window (span<=41)
    // and is in-bounds for every column (zbase <= HDIM-48 = 16). No OOB loads ever.
    const int zbase = min(zb4s[0], HDIM - WINF);

    // ---- phase 1: coalesced staging, 4-lane groups, register corner-accumulate ----
    {
        const int g = t >> 2, lane4 = t & 3;
        const float* base = input + (size_t)(b * CDIM + c0) * (size_t)VOLSZ
                          + (zbase + lane4 * 12);
        for (int s0 = 0; s0 < NSAMP; s0 += NGROUPS) {
            const int s = s0 + g;
            if (s < NSAMP) {
                const int4   cb = colb[s];
                const float4 cw = colw[s];
                const float* a0 = base + cb.x;
                const float* a1 = base + cb.y;
                const float* a2 = base + cb.z;
                const float* a3 = base + cb.w;
                f4 d0, d1, d2, d3, d4, d5;
                GLOAD0(d0, a0); GLOAD16(d1, a0); GLOAD32(d2, a0);
                GLOAD0(d3, a1); GLOAD16(d4, a1); GLOAD32(d5, a1);
                asm volatile("s_waitcnt vmcnt(0)"
                    : "+v"(d0), "+v"(d1), "+v"(d2), "+v"(d3), "+v"(d4), "+v"(d5));
                f4 acc0 = cw.x * d0 + cw.y * d3;
                f4 acc1 = cw.x * d1 + cw.y * d4;
                f4 acc2 = cw.x * d2 + cw.y * d5;
                GLOAD0(d0, a2); GLOAD16(d1, a2); GLOAD32(d2, a2);
                GLOAD0(d3, a3); GLOAD16(d4, a3); GLOAD32(d5, a3);
                asm volatile("s_waitcnt vmcnt(0)"
                    : "+v"(d0), "+v"(d1), "+v"(d2), "+v"(d3), "+v"(d4), "+v"(d5));
                acc0 += cw.z * d0 + cw.w * d3;
                acc1 += cw.z * d1 + cw.w * d4;
                acc2 += cw.z * d2 + cw.w * d5;
                float* dst = &icol[s][lane4 * 12];
                *(f4*)(dst + 0) = acc0;
                *(f4*)(dst + 4) = acc1;
                *(f4*)(dst + 8) = acc2;
            }
        }
    }
    __syncthreads();

    // ---- phase 2: z-dot from LDS ----
    if (t >= 343) return;
    const int ow = t / 49;
    const int rem = t - ow * 49;
    const int ol = rem / 7;
    const int oh = rem - ol * 7;

    const f4 zwa = *(const f4*)&zw[oh][0];
    const f4 zwb = *(const f4*)&zw[oh][4];
    const int off = zb4s[oh] - zbase;   // multiple of 4; off+8 <= 48

    float acc = 0.0f;
    #pragma unroll
    for (int dx = 0; dx < 2; ++dx) {
        #pragma unroll
        for (int dy = 0; dy < 2; ++dy) {
            const int s = (ow * 2 + dx) * 14 + (ol * 2 + dy);
            const f4 va = *(const f4*)&icol[s][off];
            const f4 vb = *(const f4*)&icol[s][off + 4];
            acc += zwa.x*va.x + zwa.y*va.y + zwa.z*va.z + zwa.w*va.w
                 + zwb.x*vb.x + zwb.y*vb.y + zwb.z*vb.z + zwb.w*vb.w;
        }
    }
    out[((size_t)(n * CDIM + c0)) * 343 + t] = acc * 0.125f;
}

extern "C" void kernel_launch(void* const* d_in, const int* in_sizes, int n_in,
                              void* d_out, int out_size, void* d_ws, size_t ws_size,
                              hipStream_t stream) {
    const float* input = (const float*)d_in[0];
    const float* rois  = (const float*)d_in[1];
    const float* scale = (const float*)d_in[2];
    float* out = (float*)d_out;
    const int N = in_sizes[1] / 8;
    dim3 grid((unsigned)(N * CDIM));
    dim3 block(384);
    hipLaunchKernelGGL(roi_align_rot3d_kernel, grid, block, 0, stream,
                       input, rois, scale, out, N);
}

// Round 5
// 450.902 us; speedup vs baseline: 1.2890x; 1.0723x over previous
//
#include <hip/hip_runtime.h>

#define OUT_W 7
#define OUT_L 7
#define OUT_H 7
#define SR 2
#define CDIM 128
#define WDIM 64
#define LDIM 64
#define HDIM 64
#define VOLSZ (WDIM * LDIM * HDIM)
#define NSAMP (OUT_W * SR * OUT_L * SR)   // 196 xy sub-samples
#define CSTRIDE 68                        // 64 data + 4 pad floats (write start-banks spread)
#define BLK 512
#define NGROUPS (BLK / 4)                 // 128 4-lane groups

typedef float f4 __attribute__((ext_vector_type(4)));

// Deep-load discipline: volatile asm loads issue back-to-back; results usable
// only through the s_waitcnt that ties exactly the loaded regs (rule #18 safe:
// consumers depend on asm outputs). Literal offsets keep 1 line/group/instr.
#define GLD0(d,p) asm volatile("global_load_dwordx4 %0, %1, off"            : "=v"(d) : "v"(p))
#define GLD1(d,p) asm volatile("global_load_dwordx4 %0, %1, off offset:64"  : "=v"(d) : "v"(p))
#define GLD2(d,p) asm volatile("global_load_dwordx4 %0, %1, off offset:128" : "=v"(d) : "v"(p))
#define GLD3(d,p) asm volatile("global_load_dwordx4 %0, %1, off offset:192" : "=v"(d) : "v"(p))

// R8: R7's separable staging with the two bugs fixed.
//  - TRUE coalescing: group's 4 lanes at +16B inside each 64B chunk; chunk step
//    via offset: immediate -> exactly 1 cache line per group per VMEM instr.
//  - 64B-aligned dynamic z-window (nl in {2,3,4} 64B chunks, block-uniform):
//    zb0 = min(zb4s[0]&~15, 64-16*nl) provably covers [zb4s[0], zb4s[6]+8)
//    and stays inside the column -> no OOB, no straddle. Mean nl ~2.6 vs 4.
//  - LDS row stride 68 floats: ds_write_b128 start banks = 4*(g+l) mod 32.
// Touch model (validated R5/R6/R7 rank-order): ~2.0K line-touches/block vs
// R5's ~8K -> expect ~2x on the TA/L1-bound component.
__global__ __launch_bounds__(BLK, 4) void roi_align_rot3d_kernel(
    const float* __restrict__ input, const float* __restrict__ rois,
    const float* __restrict__ scale_ptr, float* __restrict__ out, int N)
{
    __shared__ int4   colb[NSAMP];                      // 4 corner column bases
    __shared__ float4 colw[NSAMP];                      // 4 corner xy-weights
    __shared__ alignas(16) float icol[NSAMP][CSTRIDE];  // 53,312 B interpolated columns
    __shared__ alignas(16) float zw[OUT_H][8];          // 8-tap z filters
    __shared__ int zb4s[OUT_H];                         // per-bin aligned window base

    // bijective XCD-chunked remap (R5: FETCH 610->138 MB; keep)
    const int nwg = N * CDIM;
    const int q = nwg >> 3, rr = nwg & 7;
    const int xcd = blockIdx.x & 7;
    const int idx_in = blockIdx.x >> 3;
    const int wk = (xcd < rr ? xcd * (q + 1) : rr * (q + 1) + (xcd - rr) * q) + idx_in;
    const int c0 = wk / N;          // channel: slow axis (slice stays in XCD L2)
    const int n  = wk - c0 * N;     // ROI: fast axis (cross-ROI L2 reuse)
    const int t = threadIdx.x;

    const float scale = scale_ptr[0];
    const float* r = rois + (size_t)n * 8;
    const int   b  = (int)r[0];
    const float cx = r[1] * scale, cy = r[2] * scale, cz = r[3] * scale;
    const float sx = r[4] * scale, sy = r[5] * scale, szv = r[6] * scale;
    const float th = r[7];
    const float ct = cosf(th), st = sinf(th);

    if (t < NSAMP) {
        const int isx = t / 14, isy = t - isx * 14;
        const float xx = -0.5f * sx + ((float)isx + 0.5f) * (sx * (1.0f / 14.0f));
        const float yy = -0.5f * sy + ((float)isy + 0.5f) * (sy * (1.0f / 14.0f));
        float x = ct * xx - st * yy + cx;
        float y = st * xx + ct * yy + cy;
        const bool v = (x > -1.0f) && (x < (float)WDIM) && (y > -1.0f) && (y < (float)LDIM);
        x = fminf(fmaxf(x, 0.0f), (float)(WDIM - 1));
        y = fminf(fmaxf(y, 0.0f), (float)(LDIM - 1));
        const int x0 = (int)floorf(x);
        const int y0 = (int)floorf(y);
        const int x1 = min(x0 + 1, WDIM - 1);
        const int y1 = min(y0 + 1, LDIM - 1);
        const float lx = x - (float)x0, ly = y - (float)y0;
        const float hx = 1.0f - lx, hy = 1.0f - ly;
        const float vm = v ? 1.0f : 0.0f;
        int4 cb;
        cb.x = x0 * (LDIM * HDIM) + y0 * HDIM;
        cb.y = x1 * (LDIM * HDIM) + y0 * HDIM;
        cb.z = x0 * (LDIM * HDIM) + y1 * HDIM;
        cb.w = x1 * (LDIM * HDIM) + y1 * HDIM;
        colb[t] = cb;
        float4 cw;
        cw.x = hx * hy * vm; cw.y = lx * hy * vm;
        cw.z = hx * ly * vm; cw.w = lx * ly * vm;
        colw[t] = cw;
    } else if (t < NSAMP + OUT_H) {   // one thread per z-bin: fold 2 sub-samples x 2 taps
        const int oh = t - NSAMP;
        float w8[8];
        #pragma unroll
        for (int k = 0; k < 8; ++k) w8[k] = 0.0f;
        int zb4 = 0;
        #pragma unroll
        for (int dz = 0; dz < 2; ++dz) {
            const int s = oh * 2 + dz;
            const float zraw = -0.5f * szv + ((float)s + 0.5f) * (szv * (1.0f / 14.0f)) + cz;
            const bool v = (zraw > -1.0f) && (zraw < (float)HDIM);
            const float z = fminf(fmaxf(zraw, 0.0f), (float)(HDIM - 1));
            const int z0 = (int)floorf(z);
            const int z1 = min(z0 + 1, HDIM - 1);
            const float lz = z - (float)z0, hz = 1.0f - lz;
            const float vm = v ? 1.0f : 0.0f;
            if (dz == 0) zb4 = min(z0 & ~3, HDIM - 8);
            w8[z0 - zb4] += hz * vm;
            w8[z1 - zb4] += lz * vm;
        }
        zb4s[oh] = zb4;
        #pragma unroll
        for (int k = 0; k < 8; ++k) zw[oh][k] = w8[k];
    }
    __syncthreads();

    // Block-uniform 64B-aligned window: nl 64B chunks starting at zb0.
    // Coverage proof: if zb0==zlo16, nl-def covers zb4s[6]+8; else zb0+16nl==64>=zb4s[6]+8.
    // In-column proof: zb0>=0 (nl<=4), zb0+16nl<=64. off = zb4s[oh]-zb0 in [0,16nl-8].
    const int zlo16 = zb4s[0] & ~15;
    int nl = (zb4s[6] + 8 - zlo16 + 15) >> 4;
    if (nl < 2) nl = 2;
    const int zb0 = min(zlo16, HDIM - 16 * nl);

    // ---- phase 1: coalesced staging (1 line / group / instr), reg corner-accumulate ----
    {
        const int g = t >> 2, lane4 = t & 3;
        const float* bcol = input + (size_t)(b * CDIM + c0) * (size_t)VOLSZ
                          + zb0 + lane4 * 4;
        #pragma unroll
        for (int it = 0; it < 2; ++it) {
            const int s = g + it * NGROUPS;
            if (s < NSAMP) {
                const int4   cb = colb[s];
                const float4 cw = colw[s];
                const float* p0 = bcol + cb.x;
                const float* p1 = bcol + cb.y;
                const float* p2 = bcol + cb.z;
                const float* p3 = bcol + cb.w;
                float* dst = &icol[s][lane4 * 4];
                switch (nl) {   // block-uniform -> scalar branch
                case 2: {
                    f4 d00, d01, d10, d11, d20, d21, d30, d31;
                    GLD0(d00, p0); GLD1(d01, p0);
                    GLD0(d10, p1); GLD1(d11, p1);
                    GLD0(d20, p2); GLD1(d21, p2);
                    GLD0(d30, p3); GLD1(d31, p3);
                    asm volatile("s_waitcnt vmcnt(0)"
                        : "+v"(d00), "+v"(d01), "+v"(d10), "+v"(d11),
                          "+v"(d20), "+v"(d21), "+v"(d30), "+v"(d31));
                    *(f4*)(dst +  0) = cw.x*d00 + cw.y*d10 + cw.z*d20 + cw.w*d30;
                    *(f4*)(dst + 16) = cw.x*d01 + cw.y*d11 + cw.z*d21 + cw.w*d31;
                } break;
                case 3: {
                    f4 d00, d01, d02, d10, d11, d12, d20, d21, d22, d30, d31, d32;
                    GLD0(d00, p0); GLD1(d01, p0); GLD2(d02, p0);
                    GLD0(d10, p1); GLD1(d11, p1); GLD2(d12, p1);
                    GLD0(d20, p2); GLD1(d21, p2); GLD2(d22, p2);
                    GLD0(d30, p3); GLD1(d31, p3); GLD2(d32, p3);
                    asm volatile("s_waitcnt vmcnt(0)"
                        : "+v"(d00), "+v"(d01), "+v"(d02), "+v"(d10), "+v"(d11), "+v"(d12),
                          "+v"(d20), "+v"(d21), "+v"(d22), "+v"(d30), "+v"(d31), "+v"(d32));
                    *(f4*)(dst +  0) = cw.x*d00 + cw.y*d10 + cw.z*d20 + cw.w*d30;
                    *(f4*)(dst + 16) = cw.x*d01 + cw.y*d11 + cw.z*d21 + cw.w*d31;
                    *(f4*)(dst + 32) = cw.x*d02 + cw.y*d12 + cw.z*d22 + cw.w*d32;
                } break;
                default: {
                    f4 d00, d01, d02, d03, d10, d11, d12, d13;
                    f4 d20, d21, d22, d23, d30, d31, d32, d33;
                    GLD0(d00, p0); GLD1(d01, p0); GLD2(d02, p0); GLD3(d03, p0);
                    GLD0(d10, p1); GLD1(d11, p1); GLD2(d12, p1); GLD3(d13, p1);
                    GLD0(d20, p2); GLD1(d21, p2); GLD2(d22, p2); GLD3(d23, p2);
                    GLD0(d30, p3); GLD1(d31, p3); GLD2(d32, p3); GLD3(d33, p3);
                    asm volatile("s_waitcnt vmcnt(0)"
                        : "+v"(d00), "+v"(d01), "+v"(d02), "+v"(d03),
                          "+v"(d10), "+v"(d11), "+v"(d12), "+v"(d13),
                          "+v"(d20), "+v"(d21), "+v"(d22), "+v"(d23),
                          "+v"(d30), "+v"(d31), "+v"(d32), "+v"(d33));
                    *(f4*)(dst +  0) = cw.x*d00 + cw.y*d10 + cw.z*d20 + cw.w*d30;
                    *(f4*)(dst + 16) = cw.x*d01 + cw.y*d11 + cw.z*d21 + cw.w*d31;
                    *(f4*)(dst + 32) = cw.x*d02 + cw.y*d12 + cw.z*d22 + cw.w*d32;
                    *(f4*)(dst + 48) = cw.x*d03 + cw.y*d13 + cw.z*d23 + cw.w*d33;
                } break;
                }
            }
        }
    }
    __syncthreads();

    // ---- phase 2: z-dot from LDS ----
    if (t >= 343) return;
    const int ow = t / 49;
    const int rem = t - ow * 49;
    const int ol = rem / 7;
    const int oh = rem - ol * 7;

    const f4 zwa = *(const f4*)&zw[oh][0];
    const f4 zwb = *(const f4*)&zw[oh][4];
    const int off = zb4s[oh] - zb0;   // multiple of 4; off+8 <= 16*nl <= 64

    float acc = 0.0f;
    #pragma unroll
    for (int dx = 0; dx < 2; ++dx) {
        #pragma unroll
        for (int dy = 0; dy < 2; ++dy) {
            const int s = (ow * 2 + dx) * 14 + (ol * 2 + dy);
            const f4 va = *(const f4*)&icol[s][off];
            const f4 vb = *(const f4*)&icol[s][off + 4];
            acc += zwa.x*va.x + zwa.y*va.y + zwa.z*va.z + zwa.w*va.w
                 + zwb.x*vb.x + zwb.y*vb.y + zwb.z*vb.z + zwb.w*vb.w;
        }
    }
    out[((size_t)(n * CDIM + c0)) * 343 + t] = acc * 0.125f;
}

extern "C" void kernel_launch(void* const* d_in, const int* in_sizes, int n_in,
                              void* d_out, int out_size, void* d_ws, size_t ws_size,
                              hipStream_t stream) {
    const float* input = (const float*)d_in[0];
    const float* rois  = (const float*)d_in[1];
    const float* scale = (const float*)d_in[2];
    float* out = (float*)d_out;
    const int N = in_sizes[1] / 8;
    dim3 grid((unsigned)(N * CDIM));
    dim3 block(BLK);
    hipLaunchKernelGGL(roi_align_rot3d_kernel, grid, block, 0, stream,
                       input, rois, scale, out, N);
}